// Round 9
// baseline (283.354 us; speedup 1.0000x reference)
//
#include <hip/hip_runtime.h>

// World model (VERIFIED via round-8 absmax-channel probe, decode 19712=16384+13*256):
//   - word_vectors: float32 [16,4096,768], d_in[0], in_sizes in ELEMENTS (50331648)
//   - output: float32, out_size=1574912 = [16,128,768] vec + [16,128] mask
//   - n_in = 5; bool masks are INT32 on device (round-1 u8-read gave the
//     01-00-00-00 quarter-stride zeroing signature); rep_ids/lengths int32.
#define PB 16
#define PT 4096
#define PD 768
#define PS 64
#define NT 192   // threads per block = D/4 (float4 columns)

__global__ __launch_bounds__(NT) void pooling_kernel(
    const float* __restrict__ wv,         // [B, T, D] f32
    const int* __restrict__ rep_ids,      // [B, S] i32
    const int* __restrict__ rep_mask,     // [B, S] i32 (bool as int32)
    const int* __restrict__ lengths,      // [B, S] i32
    const int* __restrict__ len_mask,     // [B, S] i32 (bool as int32)
    float* __restrict__ out)              // [B*2S*D] f32 vec, then [B*2S] f32 mask
{
    const int blk = blockIdx.x;           // one block per (b, s)
    const int b = blk >> 6;
    const int s = blk & 63;
    const int tid = threadIdx.x;          // float4 column, 0..191

    __shared__ int sh_len[PS];
    __shared__ int sh_se[2];
    __shared__ int sh_any;

    if (tid < PS) sh_len[tid] = lengths[b * PS + tid];
    if (tid == 0) sh_any = 0;
    __syncthreads();
    if (tid == 0) {
        int start = 0;
        #pragma unroll 1
        for (int i = 0; i < s; ++i) start += sh_len[i];
        int end = start + sh_len[s];
        if (start > PT) start = PT;
        if (end > PT) end = PT;
        sh_se[0] = start;
        sh_se[1] = end;
    }
    __syncthreads();
    const int start = sh_se[0];
    const int end = sh_se[1];

    const float4* __restrict__ wv4 = (const float4*)wv;   // row stride NT
    float4* __restrict__ out4 = (float4*)out;

    // ---- mean_tokens: per-dim f32 sum + nonzero count over the span ----
    float sx = 0.f, sy = 0.f, sz = 0.f, sw = 0.f;
    int cx = 0, cy = 0, cz = 0, cw = 0;
    #pragma unroll 8
    for (int t = start; t < end; ++t) {
        float4 v = wv4[(size_t)(b * PT + t) * NT + tid];
        sx += v.x; sy += v.y; sz += v.z; sw += v.w;
        cx += (v.x != 0.f);
        cy += (v.y != 0.f);
        cz += (v.z != 0.f);
        cw += (v.w != 0.f);
    }
    if ((cx | cy | cz | cw) != 0) sh_any = 1;   // benign same-value race
    __syncthreads();
    const bool empty = (sh_any == 0);           // sentence has no nonzero entry

    const bool lm = len_mask[b * PS + s] != 0;
    float4 mv;
    if (empty) {
        mv = wv4[tid];                          // word_vectors[0,0,:] fallback
    } else {
        mv.x = sx / (cx ? (float)cx : 1.f);
        mv.y = sy / (cy ? (float)cy : 1.f);
        mv.z = sz / (cz ? (float)cz : 1.f);
        mv.w = sw / (cw ? (float)cw : 1.f);
    }
    if (!lm) { mv.x = mv.y = mv.z = mv.w = 0.f; }
    out4[((size_t)b * 2 * PS + PS + s) * NT + tid] = mv;

    // ---- sent_rep_tokens: gather rep token row (cache-hot: row 'start') ----
    const int tokid = rep_ids[b * PS + s];
    const bool rm = rep_mask[b * PS + s] != 0;
    float4 rv = wv4[(size_t)(b * PT + tokid) * NT + tid];
    if (!rm) { rv.x = rv.y = rv.z = rv.w = 0.f; }
    out4[((size_t)b * 2 * PS + s) * NT + tid] = rv;

    // ---- output mask (f32 scalars after the vector block) ----
    if (tid == 0) {
        float* out_mask = out + (size_t)PB * 2 * PS * PD;
        out_mask[b * 2 * PS + s]      = rm ? 1.f : 0.f;
        out_mask[b * 2 * PS + PS + s] = lm ? 1.f : 0.f;
    }
}

extern "C" void kernel_launch(void* const* d_in, const int* in_sizes, int n_in,
                              void* d_out, int out_size, void* d_ws, size_t ws_size,
                              hipStream_t stream) {
    const float* wv = (const float*)d_in[0];
    const int* rep_ids = (const int*)d_in[1];
    const int* rep_mask = (const int*)d_in[2];
    const int* lengths = (const int*)d_in[3];
    const int* len_mask = (const int*)d_in[4];
    float* out = (float*)d_out;

    pooling_kernel<<<dim3(PB * PS), dim3(NT), 0, stream>>>(
        wv, rep_ids, rep_mask, lengths, len_mask, out);
}

// Round 10
// 283.304 us; speedup vs baseline: 1.0002x; 1.0002x over previous
//
#include <hip/hip_runtime.h>

// World model (VERIFIED via round-8 absmax-channel probe + round-9 pass):
//   word_vectors f32 [16,4096,768]; rep_ids/lengths i32; masks i32(bool);
//   out f32: [16,128,768] vec then [16,128] mask; in_sizes in elements.
// Round-9 kernel ~46us vs ~31us stream roofline; grid-limited occupancy
// (1024 blocks x 3 waves = 12 waves/CU). This version: 576 thr/block
// (9 waves/block, ~27 waves/CU), 3 token-groups, LDS partial combine.
#define PB 16
#define PT 4096
#define PD 768
#define PS 64
#define NC 192          // float4 columns per row (768/4)
#define NG 3            // token groups per block
#define NT (NC * NG)    // 576 threads

__global__ __launch_bounds__(NT) void pooling_kernel(
    const float* __restrict__ wv,         // [B, T, D] f32
    const int* __restrict__ rep_ids,      // [B, S] i32
    const int* __restrict__ rep_mask,     // [B, S] i32 (bool)
    const int* __restrict__ lengths,      // [B, S] i32
    const int* __restrict__ len_mask,     // [B, S] i32 (bool)
    float* __restrict__ out)              // [B*2S*D] vec then [B*2S] mask
{
    const int blk = blockIdx.x;           // one block per (batch, sentence)
    const int bb = blk >> 6;
    const int s = blk & 63;
    const int tid = threadIdx.x;
    const int grp = tid / NC;             // 0..2
    const int col = tid - grp * NC;       // float4 column 0..191

    __shared__ int sh_len[PS];
    __shared__ int sh_se[2];
    __shared__ int sh_any;
    __shared__ float4 sh_sum[NG][NC];     // 9216 B
    __shared__ int4   sh_cnt[NG][NC];     // 9216 B

    if (tid < PS) sh_len[tid] = lengths[bb * PS + tid];
    if (tid == 0) sh_any = 0;
    __syncthreads();
    if (tid == 0) {
        int start = 0;
        #pragma unroll 1
        for (int i = 0; i < s; ++i) start += sh_len[i];
        int end = start + sh_len[s];
        if (start > PT) start = PT;
        if (end > PT) end = PT;
        sh_se[0] = start;
        sh_se[1] = end;
    }
    __syncthreads();
    const int start = sh_se[0];
    const int end = sh_se[1];
    const int len = end - start;
    const int chunk = (len + NG - 1) / NG;
    int t0 = start + grp * chunk;
    int t1 = t0 + chunk;
    if (t0 > end) t0 = end;
    if (t1 > end) t1 = end;

    const float4* __restrict__ wv4 = (const float4*)wv;   // row stride NC
    float4* __restrict__ out4 = (float4*)out;

    // ---- partial per-dim sum + nonzero count over this group's tokens ----
    float sx = 0.f, sy = 0.f, sz = 0.f, sw = 0.f;
    int cx = 0, cy = 0, cz = 0, cw = 0;
    #pragma unroll 4
    for (int t = t0; t < t1; ++t) {
        float4 v = wv4[(size_t)(bb * PT + t) * NC + col];
        sx += v.x; sy += v.y; sz += v.z; sw += v.w;
        cx += (v.x != 0.f);
        cy += (v.y != 0.f);
        cz += (v.z != 0.f);
        cw += (v.w != 0.f);
    }
    sh_sum[grp][col] = make_float4(sx, sy, sz, sw);
    sh_cnt[grp][col] = make_int4(cx, cy, cz, cw);
    __syncthreads();

    // ---- combine partials (fixed order: g0+g1+g2 -> deterministic) ----
    const bool lead = (tid < NC);
    float4 sm;
    int4 ct;
    if (lead) {
        float4 a = sh_sum[0][col], b = sh_sum[1][col], c = sh_sum[2][col];
        int4 ka = sh_cnt[0][col], kb = sh_cnt[1][col], kc = sh_cnt[2][col];
        sm = make_float4(a.x + b.x + c.x, a.y + b.y + c.y,
                         a.z + b.z + c.z, a.w + b.w + c.w);
        ct = make_int4(ka.x + kb.x + kc.x, ka.y + kb.y + kc.y,
                       ka.z + kb.z + kc.z, ka.w + kb.w + kc.w);
        if ((ct.x | ct.y | ct.z | ct.w) != 0) sh_any = 1;   // benign race
    }
    __syncthreads();

    if (lead) {
        const bool empty = (sh_any == 0);
        const bool lm = len_mask[bb * PS + s] != 0;
        float4 mv;
        if (empty) {
            mv = wv4[col];                       // word_vectors[0,0,:] fallback
        } else {
            mv.x = sm.x / (ct.x ? (float)ct.x : 1.f);
            mv.y = sm.y / (ct.y ? (float)ct.y : 1.f);
            mv.z = sm.z / (ct.z ? (float)ct.z : 1.f);
            mv.w = sm.w / (ct.w ? (float)ct.w : 1.f);
        }
        if (!lm) { mv.x = mv.y = mv.z = mv.w = 0.f; }
        out4[((size_t)bb * 2 * PS + PS + s) * NC + col] = mv;

        // ---- rep-token gather (row usually == start row: cache-hot) ----
        const int tokid = rep_ids[bb * PS + s];
        const bool rm = rep_mask[bb * PS + s] != 0;
        float4 rv = wv4[(size_t)(bb * PT + tokid) * NC + col];
        if (!rm) { rv.x = rv.y = rv.z = rv.w = 0.f; }
        out4[((size_t)bb * 2 * PS + s) * NC + col] = rv;

        if (col == 0) {
            float* out_mask = out + (size_t)PB * 2 * PS * PD;
            out_mask[bb * 2 * PS + s]      = rm ? 1.f : 0.f;
            out_mask[bb * 2 * PS + PS + s] = lm ? 1.f : 0.f;
        }
    }
}

extern "C" void kernel_launch(void* const* d_in, const int* in_sizes, int n_in,
                              void* d_out, int out_size, void* d_ws, size_t ws_size,
                              hipStream_t stream) {
    const float* wv = (const float*)d_in[0];
    const int* rep_ids = (const int*)d_in[1];
    const int* rep_mask = (const int*)d_in[2];
    const int* lengths = (const int*)d_in[3];
    const int* len_mask = (const int*)d_in[4];
    float* out = (float*)d_out;

    pooling_kernel<<<dim3(PB * PS), dim3(NT), 0, stream>>>(
        wv, rep_ids, rep_mask, lengths, len_mask, out);
}